// Round 1
// baseline (824.895 us; speedup 1.0000x reference)
//
#include <hip/hip_runtime.h>
#include <hip/hip_bf16.h>
#include <stdint.h>

#define NUM_CLASS 100000
#define NUM_CLASS_PAD 100096
#define EMB 512
#define BATCH 1024
#define S_SCALE 64.0f
#define T_HARD 1.2f            // T + 1
#define COS_M   0.8775825618903728f
#define SIN_M   0.479425538604203f
#define THETA_C (-0.8775825618903728f)   // cos(pi - M)
#define SINMM   0.2397127693021015f      // sin(pi - M) * M
#define COS_M1  0.9800665778412416f
#define SIN_M1  0.19866933079506122f
#define SINMM1  (-0.039733866159012244f) // sin(-M1) * M1

typedef __attribute__((ext_vector_type(8))) short bf16x8;
typedef __attribute__((ext_vector_type(4))) float floatx4;

__device__ __forceinline__ unsigned short f2bf(float f) {
    union { float f; unsigned u; } v; v.f = f;
    unsigned r = v.u + 0x7fffu + ((v.u >> 16) & 1u);
    return (unsigned short)(r >> 16);
}
__device__ __forceinline__ float blo(unsigned u) {
    union { unsigned v; float f; } c; c.v = u << 16; return c.f;
}
__device__ __forceinline__ float bhi(unsigned u) {
    union { unsigned v; float f; } c; c.v = u & 0xffff0000u; return c.f;
}
__device__ __forceinline__ void load16(const unsigned short* g, unsigned short* l) {
    __builtin_amdgcn_global_load_lds(
        (const __attribute__((address_space(1))) void*)g,
        (__attribute__((address_space(3))) void*)l, 16, 0, 0);
}

// ---- Kernel 1: normalize embeddings -> bf16 ----
__global__ void k_embed(const float* __restrict__ emb, unsigned short* __restrict__ ne) {
    int row = blockIdx.x;            // 1024
    int t = threadIdx.x;             // 256, 2 floats each
    float2 v = ((const float2*)(emb + row * EMB))[t];
    float ss = v.x * v.x + v.y * v.y;
    __shared__ float red[4];
    for (int off = 32; off; off >>= 1) ss += __shfl_down(ss, off);
    if ((t & 63) == 0) red[t >> 6] = ss;
    __syncthreads();
    float inv = rsqrtf(red[0] + red[1] + red[2] + red[3]);
    unsigned b0 = f2bf(v.x * inv), b1 = f2bf(v.y * inv);
    ((unsigned*)(ne + row * EMB))[t] = b0 | (b1 << 16);
}

// ---- Kernel 2: normalize weights -> bf16 (one wave per row, padded to 100096) ----
__global__ void k_weight(const float* __restrict__ w, unsigned short* __restrict__ nw) {
    int r = blockIdx.x * 4 + (threadIdx.x >> 6);
    int L = threadIdx.x & 63;
    uint4* dst = (uint4*)(nw + (size_t)r * EMB + L * 8);
    if (r >= NUM_CLASS) { *dst = make_uint4(0, 0, 0, 0); return; }
    const float4* src = (const float4*)(w + (size_t)r * EMB + L * 8);
    float4 a = src[0], b = src[1];
    float ss = a.x*a.x + a.y*a.y + a.z*a.z + a.w*a.w
             + b.x*b.x + b.y*b.y + b.z*b.z + b.w*b.w;
    for (int off = 32; off; off >>= 1) ss += __shfl_down(ss, off);
    ss = __shfl(ss, 0);
    float inv = rsqrtf(ss);
    uint4 o;
    o.x = (unsigned)f2bf(a.x*inv) | ((unsigned)f2bf(a.y*inv) << 16);
    o.y = (unsigned)f2bf(a.z*inv) | ((unsigned)f2bf(a.w*inv) << 16);
    o.z = (unsigned)f2bf(b.x*inv) | ((unsigned)f2bf(b.y*inv) << 16);
    o.w = (unsigned)f2bf(b.z*inv) | ((unsigned)f2bf(b.w*inv) << 16);
    *dst = o;
}

// ---- Kernel 3: target logits -> ftl, ftl1 per row (one wave per row) ----
__global__ void k_tl(const unsigned short* __restrict__ ne, const unsigned short* __restrict__ nw,
                     const int* __restrict__ labels, float* __restrict__ ftl, float* __restrict__ ftl1) {
    int b = blockIdx.x * 4 + (threadIdx.x >> 6);
    int L = threadIdx.x & 63;
    int lab = labels[b];
    uint4 ua = *(const uint4*)(ne + (size_t)b * EMB + L * 8);
    uint4 ub = *(const uint4*)(nw + (size_t)lab * EMB + L * 8);
    float s = blo(ua.x)*blo(ub.x) + bhi(ua.x)*bhi(ub.x)
            + blo(ua.y)*blo(ub.y) + bhi(ua.y)*bhi(ub.y)
            + blo(ua.z)*blo(ub.z) + bhi(ua.z)*bhi(ub.z)
            + blo(ua.w)*blo(ub.w) + bhi(ua.w)*bhi(ub.w);
    for (int off = 32; off; off >>= 1) s += __shfl_down(s, off);
    if (L == 0) {
        float tl = fminf(1.0f, fmaxf(-1.0f, s));
        float st = sqrtf(fmaxf(0.0f, 1.0f - tl * tl));
        float cos_tm  = tl * COS_M  - st * SIN_M;
        float cos_tm1 = tl * COS_M1 - st * SIN_M1;
        float f  = (tl > THETA_C)  ? cos_tm  : (tl - SINMM);
        float f1 = (tl <= COS_M1)  ? cos_tm1 : (tl + SINMM1);
        ftl[b] = f;
        ftl1[b] = f1;
    }
}

// ---- Kernel 4: bf16 MFMA GEMM 128x128 tile + fused epilogue ----
__global__ void k_gemm(const unsigned short* __restrict__ A,   // ne [1024][512]
                       const unsigned short* __restrict__ B,   // nw [100096][512]
                       const float* __restrict__ ftl, const float* __restrict__ ftl1,
                       const int* __restrict__ labels,
                       float* __restrict__ out, unsigned* __restrict__ cnt) {
    __shared__ unsigned short ldsA[128 * 32];
    __shared__ unsigned short ldsB[128 * 32];
    __shared__ float sF[128], sF1[128];
    __shared__ int sLab[128];
    __shared__ unsigned sCnt[8];

    const int tid = threadIdx.x;
    const int rowBase = blockIdx.x * 128;   // 8 tiles
    const int colBase = blockIdx.y * 128;   // 782 tiles

    if (tid < 128) {
        sF[tid]  = ftl[rowBase + tid];
        sF1[tid] = ftl1[rowBase + tid];
        sLab[tid] = labels[rowBase + tid];
    }

    const int wave = tid >> 6;
    const int lane = tid & 63;
    const int wm = wave >> 1, wn = wave & 1;
    const int rowA0 = tid >> 2;             // staging: chunk = tid, row = tid/4
    const int kc0 = (tid & 3) * 8;

    floatx4 acc[4][4] = {};

    const unsigned short* gA = A + (size_t)(rowBase + rowA0) * EMB + kc0;
    const unsigned short* gB = B + (size_t)(colBase + rowA0) * EMB + kc0;
    unsigned short* lA0 = &ldsA[tid * 8];
    unsigned short* lA1 = &ldsA[tid * 8 + 2048];
    unsigned short* lB0 = &ldsB[tid * 8];
    unsigned short* lB1 = &ldsB[tid * 8 + 2048];

    const int rA = (wm * 64 + (lane & 15)) * 32 + (lane >> 4) * 8;
    const int rB = (wn * 64 + (lane & 15)) * 32 + (lane >> 4) * 8;

    for (int kk = 0; kk < EMB; kk += 32) {
        load16(gA + kk, lA0);
        load16(gA + kk + 64 * EMB, lA1);
        load16(gB + kk, lB0);
        load16(gB + kk + 64 * EMB, lB1);
        __syncthreads();
        bf16x8 af[4], bf[4];
        #pragma unroll
        for (int mi = 0; mi < 4; mi++) af[mi] = *(const bf16x8*)&ldsA[rA + mi * 16 * 32];
        #pragma unroll
        for (int ni = 0; ni < 4; ni++) bf[ni] = *(const bf16x8*)&ldsB[rB + ni * 16 * 32];
        #pragma unroll
        for (int mi = 0; mi < 4; mi++)
            #pragma unroll
            for (int ni = 0; ni < 4; ni++)
                acc[mi][ni] = __builtin_amdgcn_mfma_f32_16x16x32_bf16(af[mi], bf[ni], acc[mi][ni], 0, 0, 0);
        __syncthreads();
    }

    // epilogue: clip, masks, counts, label override, scale, store
    unsigned cH = 0, cN = 0;
    #pragma unroll
    for (int mi = 0; mi < 4; mi++) {
        int rl = wm * 64 + mi * 16 + (lane >> 4) * 4;
        #pragma unroll
        for (int ni = 0; ni < 4; ni++) {
            int col = colBase + wn * 64 + ni * 16 + (lane & 15);
            bool cok = col < NUM_CLASS;
            floatx4 a = acc[mi][ni];
            #pragma unroll
            for (int r = 0; r < 4; r++) {
                int row = rl + r;
                float lg = fminf(1.0f, fmaxf(-1.0f, a[r]));
                float F = sF[row], F1 = sF1[row];
                bool h = lg > F, n = lg > F1;
                if (cok) {
                    cH += h; cN += n;
                    float val = n ? fmaxf(lg, 1e-30f) : (h ? lg * T_HARD : lg);
                    if (col == sLab[row]) val = F;
                    out[(size_t)(rowBase + row) * NUM_CLASS + col] = val * S_SCALE;
                }
            }
        }
    }
    for (int off = 32; off; off >>= 1) { cH += __shfl_down(cH, off); cN += __shfl_down(cN, off); }
    if (lane == 0) { sCnt[wave] = cH; sCnt[4 + wave] = cN; }
    __syncthreads();
    if (tid == 0) {
        atomicAdd(&cnt[0], sCnt[0] + sCnt[1] + sCnt[2] + sCnt[3]);
        atomicAdd(&cnt[1], sCnt[4] + sCnt[5] + sCnt[6] + sCnt[7]);
    }
}

// ---- Kernel 5: finalize scalar outputs ----
__global__ void k_final(const unsigned* __restrict__ cnt, float* __restrict__ o) {
    unsigned hard_cnt = cnt[0], noise_num = cnt[1];
    unsigned num_all = (unsigned)BATCH * (unsigned)NUM_CLASS;   // 102,400,000
    unsigned easy = num_all - hard_cnt;
    unsigned hard_num = hard_cnt - noise_num;
    float phi = ((float)easy / (float)num_all) * 0.01f;
    o[0] = (float)easy;
    o[1] = (float)noise_num;
    o[2] = (float)hard_num;
    o[3] = phi;
}

extern "C" void kernel_launch(void* const* d_in, const int* in_sizes, int n_in,
                              void* d_out, int out_size, void* d_ws, size_t ws_size,
                              hipStream_t stream) {
    const float* emb = (const float*)d_in[0];
    const float* wgt = (const float*)d_in[1];
    const int* labels = (const int*)d_in[2];
    float* out = (float*)d_out;
    char* ws = (char*)d_ws;

    unsigned* cnt = (unsigned*)ws;                           // 64 B
    float* ftl  = (float*)(ws + 64);                         // 4 KB
    float* ftl1 = (float*)(ws + 8192);                       // 4 KB
    unsigned short* ne = (unsigned short*)(ws + 16384);      // 1 MB
    unsigned short* nw = (unsigned short*)(ws + (1 << 21));  // ~102.5 MB

    hipMemsetAsync(cnt, 0, 64, stream);
    k_embed<<<BATCH, 256, 0, stream>>>(emb, ne);
    k_weight<<<NUM_CLASS_PAD / 4, 256, 0, stream>>>(wgt, nw);
    k_tl<<<BATCH / 4, 256, 0, stream>>>(ne, nw, labels, ftl, ftl1);
    k_gemm<<<dim3(8, 782), 256, 0, stream>>>(ne, nw, ftl, ftl1, labels, out, cnt);
    k_final<<<1, 1, 0, stream>>>(cnt, out + (size_t)BATCH * NUM_CLASS);
}

// Round 2
// 810.663 us; speedup vs baseline: 1.0176x; 1.0176x over previous
//
#include <hip/hip_runtime.h>
#include <hip/hip_bf16.h>
#include <stdint.h>

#define NUM_CLASS 100000
#define NUM_CLASS_PAD 100096
#define EMB 512
#define BATCH 1024
#define S_SCALE 64.0f
#define T_HARD 1.2f            // T + 1
#define COS_M   0.8775825618903728f
#define SIN_M   0.479425538604203f
#define THETA_C (-0.8775825618903728f)   // cos(pi - M)
#define SINMM   0.2397127693021015f      // sin(pi - M) * M
#define COS_M1  0.9800665778412416f
#define SIN_M1  0.19866933079506122f
#define SINMM1  (-0.039733866159012244f) // sin(-M1) * M1

typedef __attribute__((ext_vector_type(8))) short bf16x8;
typedef __attribute__((ext_vector_type(4))) float floatx4;

__device__ __forceinline__ unsigned short f2bf(float f) {
    union { float f; unsigned u; } v; v.f = f;
    unsigned r = v.u + 0x7fffu + ((v.u >> 16) & 1u);
    return (unsigned short)(r >> 16);
}
__device__ __forceinline__ float blo(unsigned u) {
    union { unsigned v; float f; } c; c.v = u << 16; return c.f;
}
__device__ __forceinline__ float bhi(unsigned u) {
    union { unsigned v; float f; } c; c.v = u & 0xffff0000u; return c.f;
}
__device__ __forceinline__ void load16(const unsigned short* g, unsigned short* l) {
    __builtin_amdgcn_global_load_lds(
        (const __attribute__((address_space(1))) void*)g,
        (__attribute__((address_space(3))) void*)l, 16, 0, 0);
}

// ---- Kernel 1: normalize embeddings -> bf16 ----
__global__ void k_embed(const float* __restrict__ emb, unsigned short* __restrict__ ne) {
    int row = blockIdx.x;            // 1024
    int t = threadIdx.x;             // 256, 2 floats each
    float2 v = ((const float2*)(emb + row * EMB))[t];
    float ss = v.x * v.x + v.y * v.y;
    __shared__ float red[4];
    for (int off = 32; off; off >>= 1) ss += __shfl_down(ss, off);
    if ((t & 63) == 0) red[t >> 6] = ss;
    __syncthreads();
    float inv = rsqrtf(red[0] + red[1] + red[2] + red[3]);
    unsigned b0 = f2bf(v.x * inv), b1 = f2bf(v.y * inv);
    ((unsigned*)(ne + row * EMB))[t] = b0 | (b1 << 16);
}

// ---- Kernel 2: normalize weights -> bf16 (one wave per row, padded to 100096) ----
__global__ void k_weight(const float* __restrict__ w, unsigned short* __restrict__ nw) {
    int r = blockIdx.x * 4 + (threadIdx.x >> 6);
    int L = threadIdx.x & 63;
    uint4* dst = (uint4*)(nw + (size_t)r * EMB + L * 8);
    if (r >= NUM_CLASS) { *dst = make_uint4(0, 0, 0, 0); return; }
    const float4* src = (const float4*)(w + (size_t)r * EMB + L * 8);
    float4 a = src[0], b = src[1];
    float ss = a.x*a.x + a.y*a.y + a.z*a.z + a.w*a.w
             + b.x*b.x + b.y*b.y + b.z*b.z + b.w*b.w;
    for (int off = 32; off; off >>= 1) ss += __shfl_down(ss, off);
    ss = __shfl(ss, 0);
    float inv = rsqrtf(ss);
    uint4 o;
    o.x = (unsigned)f2bf(a.x*inv) | ((unsigned)f2bf(a.y*inv) << 16);
    o.y = (unsigned)f2bf(a.z*inv) | ((unsigned)f2bf(a.w*inv) << 16);
    o.z = (unsigned)f2bf(b.x*inv) | ((unsigned)f2bf(b.y*inv) << 16);
    o.w = (unsigned)f2bf(b.z*inv) | ((unsigned)f2bf(b.w*inv) << 16);
    *dst = o;
}

// ---- Kernel 3: target logits -> ftl, ftl1 per row (one wave per row) ----
__global__ void k_tl(const unsigned short* __restrict__ ne, const unsigned short* __restrict__ nw,
                     const int* __restrict__ labels, float* __restrict__ ftl, float* __restrict__ ftl1) {
    int b = blockIdx.x * 4 + (threadIdx.x >> 6);
    int L = threadIdx.x & 63;
    int lab = labels[b];
    uint4 ua = *(const uint4*)(ne + (size_t)b * EMB + L * 8);
    uint4 ub = *(const uint4*)(nw + (size_t)lab * EMB + L * 8);
    float s = blo(ua.x)*blo(ub.x) + bhi(ua.x)*bhi(ub.x)
            + blo(ua.y)*blo(ub.y) + bhi(ua.y)*bhi(ub.y)
            + blo(ua.z)*blo(ub.z) + bhi(ua.z)*bhi(ub.z)
            + blo(ua.w)*blo(ub.w) + bhi(ua.w)*bhi(ub.w);
    for (int off = 32; off; off >>= 1) s += __shfl_down(s, off);
    if (L == 0) {
        float tl = fminf(1.0f, fmaxf(-1.0f, s));
        float st = sqrtf(fmaxf(0.0f, 1.0f - tl * tl));
        float cos_tm  = tl * COS_M  - st * SIN_M;
        float cos_tm1 = tl * COS_M1 - st * SIN_M1;
        float f  = (tl > THETA_C)  ? cos_tm  : (tl - SINMM);
        float f1 = (tl <= COS_M1)  ? cos_tm1 : (tl + SINMM1);
        ftl[b] = f;
        ftl1[b] = f1;
    }
}

// ---- Kernel 4: bf16 MFMA GEMM 128x128 tile + fused epilogue ----
// Operand-swapped MFMA: acc holds C^T fragment => each lane owns 4 CONSECUTIVE
// class-columns of one batch-row => float4 nontemporal stores.
__global__ void k_gemm(const unsigned short* __restrict__ A,   // ne [1024][512]
                       const unsigned short* __restrict__ B,   // nw [100096][512]
                       const float* __restrict__ ftl, const float* __restrict__ ftl1,
                       const int* __restrict__ labels,
                       float* __restrict__ out, unsigned* __restrict__ cnt) {
    __shared__ unsigned short ldsA[128 * 32];
    __shared__ unsigned short ldsB[128 * 32];
    __shared__ float sF[128], sF1[128];
    __shared__ int sLab[128];
    __shared__ unsigned sCnt[8];

    const int tid = threadIdx.x;
    const int rowBase = blockIdx.x * 128;   // 8 tiles
    const int colBase = blockIdx.y * 128;   // 782 tiles

    if (tid < 128) {
        sF[tid]  = ftl[rowBase + tid];
        sF1[tid] = ftl1[rowBase + tid];
        sLab[tid] = labels[rowBase + tid];
    }

    const int wave = tid >> 6;
    const int lane = tid & 63;
    const int wm = wave >> 1, wn = wave & 1;
    const int rowA0 = tid >> 2;             // staging: chunk = tid, row = tid/4
    const int kc0 = (tid & 3) * 8;

    floatx4 acc[4][4] = {};

    const unsigned short* gA = A + (size_t)(rowBase + rowA0) * EMB + kc0;
    const unsigned short* gB = B + (size_t)(colBase + rowA0) * EMB + kc0;
    unsigned short* lA0 = &ldsA[tid * 8];
    unsigned short* lA1 = &ldsA[tid * 8 + 2048];
    unsigned short* lB0 = &ldsB[tid * 8];
    unsigned short* lB1 = &ldsB[tid * 8 + 2048];

    const int rA = (wm * 64 + (lane & 15)) * 32 + (lane >> 4) * 8;
    const int rB = (wn * 64 + (lane & 15)) * 32 + (lane >> 4) * 8;

    for (int kk = 0; kk < EMB; kk += 32) {
        load16(gA + kk, lA0);
        load16(gA + kk + 64 * EMB, lA1);
        load16(gB + kk, lB0);
        load16(gB + kk + 64 * EMB, lB1);
        __syncthreads();
        bf16x8 af[4], bf[4];
        #pragma unroll
        for (int mi = 0; mi < 4; mi++) af[mi] = *(const bf16x8*)&ldsA[rA + mi * 16 * 32];
        #pragma unroll
        for (int ni = 0; ni < 4; ni++) bf[ni] = *(const bf16x8*)&ldsB[rB + ni * 16 * 32];
        // swapped operands: D = (B-rows) x (A-rows)^T  => lane&15 = batch row,
        // (lane>>4)*4 + r = class col (4 consecutive cols per lane)
        #pragma unroll
        for (int mi = 0; mi < 4; mi++)
            #pragma unroll
            for (int ni = 0; ni < 4; ni++)
                acc[mi][ni] = __builtin_amdgcn_mfma_f32_16x16x32_bf16(bf[ni], af[mi], acc[mi][ni], 0, 0, 0);
        __syncthreads();
    }

    // epilogue: clip, masks, counts, label override, scale, float4 nt store
    unsigned cH = 0, cN = 0;
    #pragma unroll
    for (int mi = 0; mi < 4; mi++) {
        const int row = wm * 64 + mi * 16 + (lane & 15);
        const float F = sF[row], F1 = sF1[row];
        const int lab = sLab[row];
        float* orow = out + (size_t)(rowBase + row) * NUM_CLASS;
        #pragma unroll
        for (int ni = 0; ni < 4; ni++) {
            const int col = colBase + wn * 64 + ni * 16 + (lane >> 4) * 4;
            if (col < NUM_CLASS) {     // 100000 % 4 == 0: chunk fully in or out
                floatx4 a = acc[mi][ni];
                floatx4 v;
                #pragma unroll
                for (int r = 0; r < 4; r++) {
                    float lg = fminf(1.0f, fmaxf(-1.0f, a[r]));
                    bool h = lg > F, n = lg > F1;
                    cH += h; cN += n;
                    float val = n ? fmaxf(lg, 1e-30f) : (h ? lg * T_HARD : lg);
                    if (col + r == lab) val = F;
                    v[r] = val * S_SCALE;
                }
                __builtin_nontemporal_store(v, (floatx4*)(orow + col));
            }
        }
    }
    for (int off = 32; off; off >>= 1) { cH += __shfl_down(cH, off); cN += __shfl_down(cN, off); }
    if (lane == 0) { sCnt[wave] = cH; sCnt[4 + wave] = cN; }
    __syncthreads();
    if (tid == 0) {
        atomicAdd(&cnt[0], sCnt[0] + sCnt[1] + sCnt[2] + sCnt[3]);
        atomicAdd(&cnt[1], sCnt[4] + sCnt[5] + sCnt[6] + sCnt[7]);
    }
}

// ---- Kernel 5: finalize scalar outputs ----
__global__ void k_final(const unsigned* __restrict__ cnt, float* __restrict__ o) {
    unsigned hard_cnt = cnt[0], noise_num = cnt[1];
    unsigned num_all = (unsigned)BATCH * (unsigned)NUM_CLASS;   // 102,400,000
    unsigned easy = num_all - hard_cnt;
    unsigned hard_num = hard_cnt - noise_num;
    float phi = ((float)easy / (float)num_all) * 0.01f;
    o[0] = (float)easy;
    o[1] = (float)noise_num;
    o[2] = (float)hard_num;
    o[3] = phi;
}

extern "C" void kernel_launch(void* const* d_in, const int* in_sizes, int n_in,
                              void* d_out, int out_size, void* d_ws, size_t ws_size,
                              hipStream_t stream) {
    const float* emb = (const float*)d_in[0];
    const float* wgt = (const float*)d_in[1];
    const int* labels = (const int*)d_in[2];
    float* out = (float*)d_out;
    char* ws = (char*)d_ws;

    unsigned* cnt = (unsigned*)ws;                           // 64 B
    float* ftl  = (float*)(ws + 64);                         // 4 KB
    float* ftl1 = (float*)(ws + 8192);                       // 4 KB
    unsigned short* ne = (unsigned short*)(ws + 16384);      // 1 MB
    unsigned short* nw = (unsigned short*)(ws + (1 << 21));  // ~102.5 MB

    hipMemsetAsync(cnt, 0, 64, stream);
    k_embed<<<BATCH, 256, 0, stream>>>(emb, ne);
    k_weight<<<NUM_CLASS_PAD / 4, 256, 0, stream>>>(wgt, nw);
    k_tl<<<BATCH / 4, 256, 0, stream>>>(ne, nw, labels, ftl, ftl1);
    k_gemm<<<dim3(8, 782), 256, 0, stream>>>(ne, nw, ftl, ftl1, labels, out, cnt);
    k_final<<<1, 1, 0, stream>>>(cnt, out + (size_t)BATCH * NUM_CLASS);
}